// Round 5
// baseline (136.376 us; speedup 1.0000x reference)
//
#include <hip/hip_runtime.h>

// PatchMatch brute-force NN on MI355X.
// s,t (4,16,64,64) fp32; descriptor = 3x3 replicate-padded patch, K=144.
// d2(i,j) = qn_i - 2*cross(i,j) + pn_j; argmin_j (ties -> smallest j).
// Outputs (flat, ALL FLOAT32): nnf (4,2,64,64) then nnd (4,1,64,64).
//
// R17 vs R16 (60.8us, MfmaUtil 40%): time proved invariant to phase
// structure (R12 64.9 / R13 63.3 / R16 60.8) -> the stall is the sync
// structure itself (barrier skew + lgkm/vmcnt rendezvous) with only
// 2 waves/SIMD to cover it. B panel is L2/L1-resident (0.6MB/split), so
// LDS staging is staging-what-caches (Common-mistake #7). R17 deletes it:
//  - NO LDS B buffers, NO barriers in the main loop, NO DMA: each wave
//    streams B fragments straight from global (f16x8, two 512B segments
//    per instr; 4 waves/CU re-read same lines -> L1 hits).
//  - waves fully independent; compiler pipelines loads under MFMAs with
//    ordered partial vmcnt waits; 2 waves/SIMD overlap freely.
//  - pair of j-tiles per iteration (C0/C1 MFMA ILP), 16 iterations.
//  - LDS = pnS 4KB only. VGPR ~180-210 under launch_bounds(256,2).
//  - direct-B addressing == R14/R15 chunk-8 path (verified correct).

#define N_  4
#define C_  16
#define H_  64
#define W_  64
#define HW_ 4096
#define KK_ 18               // kk blocks of 8 (K=144)
#define SPLITS_M 4           // j-splits; 1024 j per split
#define SPLITS_V 4           // fallback j-splits
#define TILES_PER_SPLIT_V 4

typedef _Float16 f16;
typedef _Float16 f16x8 __attribute__((ext_vector_type(8)));
typedef float    f32x4 __attribute__((ext_vector_type(4)));
typedef float    f32x16 __attribute__((ext_vector_type(16)));

__device__ __forceinline__ int iclamp(int v, int lo, int hi) {
    return v < lo ? lo : (v > hi ? hi : v);
}

// ---------------------------------------------------------------------------
// Kernel 1: K-major fp16 hi/lo descriptors + squared norms.
// D[(n*18 + kk)*4096 + pix][8], kk = k/8, k = d*16 + c (d = dy*3+dx).
// One block per image row; wave q handles kk = q*5..q*5+4 for all 64 px ->
// every store is a 1KB coalesced wavefront store. grid (64, N_, 2).
// ---------------------------------------------------------------------------
__global__ __launch_bounds__(256)
void build_desc_norms_kernel(const float* __restrict__ s,
                             const float* __restrict__ t,
                             f16* __restrict__ Qh, f16* __restrict__ Ql,
                             f16* __restrict__ Ph, f16* __restrict__ Pl,
                             float* __restrict__ pn,
                             float* __restrict__ qn) {
    const int y0  = blockIdx.x;                 // image row
    const int n   = blockIdx.y;
    const int src = blockIdx.z;                 // 0: t, 1: s
    const float* img = (src ? s : t) + n * (C_ * HW_);
    f16* Dh = src ? Qh : Ph;
    f16* Dl = src ? Ql : Pl;
    float* nrm = src ? qn : pn;

    __shared__ float imgS[3][C_][W_];           // 12 KB: rows y0-1..y0+1
    __shared__ float nS[4][W_];
    const int tid = threadIdx.x;
    #pragma unroll
    for (int k = 0; k < 12; ++k) {
        const int idx = tid + k * 256;          // 0..3071
        const int x = idx & 63, c = (idx >> 6) & 15, r = idx >> 10;  // r 0..2
        const int gy = iclamp(y0 + r - 1, 0, H_ - 1);
        imgS[r][c][x] = img[c * HW_ + gy * W_ + x];
    }
    __syncthreads();

    const int q = tid >> 6, x = tid & 63;       // wave, lane(=pixel x)
    const int pix = y0 * W_ + x;
    float nacc = 0.f;
    #pragma unroll
    for (int u = 0; u < 5; ++u) {
        const int kk = q * 5 + u;               // 0..19
        if (kk < KK_) {
            f16x8 hv, lv;
            const int d  = kk >> 1;             // 0..8
            const int c0 = (kk & 1) * 8;
            const int dy = (d * 11) >> 5;       // d/3 for d in [0,8]
            const int dx = d - dy * 3;
            const int xs = iclamp(x + dx - 1, 0, W_ - 1);
            #pragma unroll
            for (int cc = 0; cc < 8; ++cc) {
                const float v = imgS[dy][c0 + cc][xs];
                const f16 h = (f16)v;
                hv[cc] = h;
                lv[cc] = (f16)(v - (float)h);
                nacc += v * v;
            }
            const size_t off = ((size_t)(n * KK_ + kk) * HW_ + pix) * 8;
            *(f16x8*)&Dh[off] = hv;             // 64 lanes x 16B contiguous
            *(f16x8*)&Dl[off] = lv;
        }
    }
    nS[q][x] = nacc;
    __syncthreads();
    if (tid < W_)
        nrm[n * HW_ + pix] = nS[0][tid] + nS[1][tid] + nS[2][tid] + nS[3][tid];
}

// ---------------------------------------------------------------------------
// Kernel 2: MFMA GEMM + fused argmax, barrier-free B streaming.
// 1D grid 512 (split=bid&3, XCD affinity under round-robin); block = 4
// waves, wave = one 32-row output stripe x 1024 j, fully independent.
// Per iteration: two 32-wide j-tiles; 36 f16x8 global B loads (L1/L2-hot)
// interleaved by the compiler with 54 MFMAs (C0/C1 ILP-2 chains).
// mfma_f32_32x32x16_f16: A/B [idx=lane&31][k=(lane>>5)*8+e];
// C col=lane&31, row=(reg&3)+8*(reg>>2)+4*(lane>>5).
// Cf initialized to -pn_j/2: argmin d2 == argmax Cf; partial stores -2*Cf.
// ---------------------------------------------------------------------------
__global__ __launch_bounds__(256, 2)
void mfma_nn_kernel(const f16* __restrict__ Qh, const f16* __restrict__ Ql,
                    const f16* __restrict__ Ph, const f16* __restrict__ Pl,
                    const float* __restrict__ pn_g,
                    unsigned long long* __restrict__ partial) {
    const int bid   = blockIdx.x;
    const int split = bid & 3;          // XCD affinity under round-robin
    const int n     = (bid >> 2) & 3;
    const int iblk  = bid >> 4;         // 0..31
    const int tid  = threadIdx.x;
    const int wave = tid >> 6, lane = tid & 63;
    const int col  = lane & 31;         // A row / B col / C col
    const int half = lane >> 5;         // k-half within a 16-chunk
    const int irow0 = iblk * 128 + wave * 32;

    __shared__ float pnS[1024];         // this split's pn (only LDS use)

    // ---- A fragments, resident (72 VGPR): 9 chunks of K=16 ----
    f16x8 Ah[9], Al[9];
    #pragma unroll
    for (int c = 0; c < 9; ++c) {
        const size_t off = ((size_t)(n * KK_ + 2 * c + half) * HW_ +
                            irow0 + col) * 8;
        Ah[c] = *(const f16x8*)(Qh + off);
        Al[c] = *(const f16x8*)(Ql + off);
    }

    const int jsplit0 = split * 1024;
    #pragma unroll
    for (int k = 0; k < 4; ++k)
        pnS[tid + k * 256] = pn_g[n * HW_ + jsplit0 + tid + k * 256];
    __syncthreads();                    // one-time: pnS visible

    float    bd[16];
    unsigned bj[16];
    #pragma unroll
    for (int r = 0; r < 16; ++r) { bd[r] = -3.0e38f; bj[r] = 0u; }

    // per-lane B base pointers: row (kk=half), col; chunk c adds 2 rows,
    // tile adds 32 cols. (element offsets: c -> c*2*HW_*8, tile -> 256)
    const f16* __restrict__ bhb =
        Ph + ((size_t)(n * KK_ + half) * HW_ + jsplit0 + col) * 8;
    const f16* __restrict__ blb =
        Pl + ((size_t)(n * KK_ + half) * HW_ + jsplit0 + col) * 8;

    #pragma unroll 2
    for (int p = 0; p < 16; ++p) {      // 16 pairs of 32-wide j-tiles
        const int j0 = p * 64 + col;    // C0's j (local); C1 = j0+32
        const float pnv0 = -0.5f * pnS[j0];
        const float pnv1 = -0.5f * pnS[j0 + 32];
        f32x16 C0, C1;
        #pragma unroll
        for (int r = 0; r < 16; ++r) { C0[r] = pnv0; C1[r] = pnv1; }
        const f16* ph = bhb + p * 512;  // 2 tiles = 64 j x 8 f16
        const f16* pl = blb + p * 512;
        #pragma unroll
        for (int c = 0; c < 9; ++c) {
            const size_t co = (size_t)c * (2 * HW_ * 8);
            const f16x8 bh0 = *(const f16x8*)(ph + co);
            const f16x8 bh1 = *(const f16x8*)(ph + co + 256);
            const f16x8 bl0 = *(const f16x8*)(pl + co);
            const f16x8 bl1 = *(const f16x8*)(pl + co + 256);
            C0 = __builtin_amdgcn_mfma_f32_32x32x16_f16(Ah[c], bh0, C0, 0, 0, 0);
            C1 = __builtin_amdgcn_mfma_f32_32x32x16_f16(Ah[c], bh1, C1, 0, 0, 0);
            C0 = __builtin_amdgcn_mfma_f32_32x32x16_f16(Al[c], bh0, C0, 0, 0, 0);
            C1 = __builtin_amdgcn_mfma_f32_32x32x16_f16(Al[c], bh1, C1, 0, 0, 0);
            C0 = __builtin_amdgcn_mfma_f32_32x32x16_f16(Ah[c], bl0, C0, 0, 0, 0);
            C1 = __builtin_amdgcn_mfma_f32_32x32x16_f16(Ah[c], bl1, C1, 0, 0, 0);
        }
        #pragma unroll
        for (int r = 0; r < 16; ++r) {
            if (C0[r] > bd[r]) { bd[r] = C0[r]; bj[r] = (unsigned)j0; }
            if (C1[r] > bd[r]) { bd[r] = C1[r]; bj[r] = (unsigned)(j0 + 32); }
        }
    }

    // ---- argmax reduce across the 32 cols (lanes col=0..31 per half) ----
    #pragma unroll
    for (int r = 0; r < 16; ++r) {
        float    d = bd[r];
        unsigned j = (unsigned)jsplit0 + bj[r];
        #pragma unroll
        for (int off = 1; off < 32; off <<= 1) {
            const float    od = __shfl_xor(d, off, 64);
            const unsigned oj = __shfl_xor(j, off, 64);
            const bool take = (od > d) || (od == d && oj < j);
            d = take ? od : d;
            j = take ? oj : j;
        }
        if (col == 0) {
            const int i = irow0 + (r & 3) + 8 * (r >> 2) + 4 * half;
            partial[(size_t)(split * N_ + n) * HW_ + i] =
                ((unsigned long long)j << 32) |
                (unsigned long long)__float_as_uint(-2.f * d);
        }
    }
}

// ---------------------------------------------------------------------------
// Kernel 3: reduce splits, add qn, decode, write outputs (float32)
// ---------------------------------------------------------------------------
__global__ __launch_bounds__(256)
void finalize_mfma_kernel(const unsigned long long* __restrict__ partial,
                          const float* __restrict__ qn_g,
                          float* __restrict__ out) {
    const int id  = blockIdx.x * 256 + threadIdx.x;   // 0..16383
    const int n   = id >> 12;
    const int pix = id & 4095;
    float    bd = 3.0e38f;
    unsigned bj = 0u;
    #pragma unroll
    for (int sp = 0; sp < SPLITS_M; ++sp) {
        const unsigned long long v = partial[(size_t)(sp * N_ + n) * HW_ + pix];
        const float    d = __uint_as_float((unsigned)(v & 0xffffffffull));
        const unsigned j = (unsigned)(v >> 32);
        const bool take = (d < bd) || (d == bd && j < bj);
        bd = take ? d : bd;
        bj = take ? j : bj;
    }
    out[n * 2 * HW_ + pix]            = (float)(bj >> 6);          // idy
    out[n * 2 * HW_ + HW_ + pix]      = (float)(bj & 63);          // idx_x
    out[N_ * 2 * HW_ + n * HW_ + pix] = bd + qn_g[n * HW_ + pix];  // nnd
}

// ===========================================================================
// Fallback path (fp32 vector) + helpers — unchanged
// ===========================================================================
__global__ __launch_bounds__(256)
void prep_norms_kernel(const float* __restrict__ s,
                       const float* __restrict__ t,
                       float* __restrict__ pn,
                       float* __restrict__ qn) {
    const int gid   = blockIdx.x * 256 + threadIdx.x;
    const int which = gid >> 14;
    const int id    = gid & 16383;
    const int n     = id >> 12;
    const int pix   = id & 4095;
    const int y = pix >> 6, x = pix & 63;
    const float* base = (which ? s : t) + n * (C_ * HW_);
    float acc = 0.f;
    for (int c = 0; c < C_; ++c) {
        const float* bc = base + c * HW_;
        #pragma unroll
        for (int dy = 0; dy < 3; ++dy) {
            const float* br = bc + iclamp(y + dy - 1, 0, H_ - 1) * W_;
            #pragma unroll
            for (int dx = 0; dx < 3; ++dx) {
                float v = br[iclamp(x + dx - 1, 0, W_ - 1)];
                acc += v * v;
            }
        }
    }
    (which ? qn : pn)[id] = acc;
}

__global__ __launch_bounds__(256)
void patchmatch_main_kernel(const float* __restrict__ s,
                            const float* __restrict__ t,
                            const float* __restrict__ pn_g,
                            const float* __restrict__ qn_g,
                            unsigned long long* __restrict__ partial) {
    const int yq    = blockIdx.x;
    const int n     = blockIdx.y;
    const int split = blockIdx.z;
    const int tid  = threadIdx.x;
    const int tx   = tid & 15;
    const int ty   = tid >> 4;
    const int i0   = ty * 4;
    const int jrow = tx >> 2;
    const int jx0  = (tx & 3) * 16;

    __shared__ float qS[C_][3][68];
    __shared__ float tS[C_][6][68];
    __shared__ float qnS[W_];

    const float* sb = s + n * (C_ * HW_);
    const float* tb = t + n * (C_ * HW_);

    #pragma unroll
    for (int k = 0; k < 3; ++k) {
        const int id = tid + k * 256;
        const int sg = id & 15;
        const int c  = (id >> 4) & 15;
        const int r  = id >> 8;
        const int gr = iclamp(yq + r - 1, 0, H_ - 1);
        const float4 v = *(const float4*)&sb[c * HW_ + gr * W_ + sg * 4];
        float* dst = &qS[c][r][1 + sg * 4];
        dst[0] = v.x; dst[1] = v.y; dst[2] = v.z; dst[3] = v.w;
    }
    if (tid < 48) {
        const int c  = tid & 15;
        const int r  = tid >> 4;
        const int gr = iclamp(yq + r - 1, 0, H_ - 1);
        qS[c][r][0]  = sb[c * HW_ + gr * W_];
        qS[c][r][65] = sb[c * HW_ + gr * W_ + 63];
    }
    if (tid < W_) qnS[tid] = qn_g[n * HW_ + yq * W_ + tid];

    unsigned long long best[4] = {~0ull, ~0ull, ~0ull, ~0ull};

    for (int ytl = 0; ytl < TILES_PER_SPLIT_V; ++ytl) {
        const int yt = split * TILES_PER_SPLIT_V + ytl;
        __syncthreads();
        #pragma unroll
        for (int k = 0; k < 6; ++k) {
            const int id = tid + k * 256;
            const int sg = id & 15;
            const int c  = (id >> 4) & 15;
            const int r  = id >> 8;
            const int gr = iclamp(4 * yt + r - 1, 0, H_ - 1);
            const float4 v = *(const float4*)&tb[c * HW_ + gr * W_ + sg * 4];
            float* dst = &tS[c][r][1 + sg * 4];
            dst[0] = v.x; dst[1] = v.y; dst[2] = v.z; dst[3] = v.w;
        }
        if (tid < 96) {
            const int c  = tid & 15;
            const int r  = tid >> 4;
            const int gr = iclamp(4 * yt + r - 1, 0, H_ - 1);
            tS[c][r][0]  = tb[c * HW_ + gr * W_];
            tS[c][r][65] = tb[c * HW_ + gr * W_ + 63];
        }
        __syncthreads();

        float acc[4][16];
        #pragma unroll
        for (int a = 0; a < 4; ++a)
            #pragma unroll
            for (int b = 0; b < 16; ++b) acc[a][b] = 0.f;

        for (int c = 0; c < C_; ++c) {
            #pragma unroll
            for (int dy = 0; dy < 3; ++dy) {
                float qv[6], tv[18];
                *(float4*)&qv[0] = *(const float4*)&qS[c][dy][i0];
                *(float2*)&qv[4] = *(const float2*)&qS[c][dy][i0 + 4];
                const float* trow = &tS[c][jrow + dy][jx0];
                *(float4*)&tv[0]  = *(const float4*)&trow[0];
                *(float4*)&tv[4]  = *(const float4*)&trow[4];
                *(float4*)&tv[8]  = *(const float4*)&trow[8];
                *(float4*)&tv[12] = *(const float4*)&trow[12];
                *(float2*)&tv[16] = *(const float2*)&trow[16];
                #pragma unroll
                for (int dx = 0; dx < 3; ++dx)
                    #pragma unroll
                    for (int a = 0; a < 4; ++a)
                        #pragma unroll
                        for (int b = 0; b < 16; ++b)
                            acc[a][b] += qv[a + dx] * tv[b + dx];
            }
        }

        const int jbase = yt * 256 + jrow * W_ + jx0;
        float pnv[16];
        const float* png = &pn_g[n * HW_ + jbase];
        *(float4*)&pnv[0]  = *(const float4*)&png[0];
        *(float4*)&pnv[4]  = *(const float4*)&png[4];
        *(float4*)&pnv[8]  = *(const float4*)&png[8];
        *(float4*)&pnv[12] = *(const float4*)&png[12];
        #pragma unroll
        for (int a = 0; a < 4; ++a) {
            const float qn = qnS[i0 + a];
            #pragma unroll
            for (int b = 0; b < 16; ++b) {
                const float d2 = qn + pnv[b] - 2.f * acc[a][b];
                unsigned long long cand =
                    ((unsigned long long)__float_as_uint(d2) << 32) |
                    (unsigned)(jbase + b);
                best[a] = cand < best[a] ? cand : best[a];
            }
        }
    }

    #pragma unroll
    for (int a = 0; a < 4; ++a) {
        unsigned long long v = best[a];
        #pragma unroll
        for (int mm = 8; mm >= 1; mm >>= 1) {
            unsigned long long o = __shfl_xor(v, mm, 64);
            v = o < v ? o : v;
        }
        best[a] = v;
    }
    if (tx == 0) {
        #pragma unroll
        for (int a = 0; a < 4; ++a)
            partial[((split * N_ + n) * HW_) + yq * W_ + i0 + a] = best[a];
    }
}

__global__ __launch_bounds__(256)
void finalize_kernel(const unsigned long long* __restrict__ partial,
                     float* __restrict__ out) {
    const int id  = blockIdx.x * 256 + threadIdx.x;
    const int n   = id >> 12;
    const int pix = id & 4095;
    unsigned long long best = ~0ull;
    #pragma unroll
    for (int sp = 0; sp < SPLITS_V; ++sp) {
        unsigned long long v = partial[(sp * N_ + n) * HW_ + pix];
        best = v < best ? v : best;
    }
    const unsigned j = (unsigned)(best & 0xffffffffu);
    const float d2 = __uint_as_float((unsigned)(best >> 32));
    out[n * 2 * HW_ + pix]            = (float)(j >> 6);
    out[n * 2 * HW_ + HW_ + pix]      = (float)(j & 63);
    out[N_ * 2 * HW_ + n * HW_ + pix] = d2;
}

__global__ __launch_bounds__(256)
void patchmatch_mono_kernel(const float* __restrict__ s,
                            const float* __restrict__ t,
                            float* __restrict__ out) {
    const int yq  = blockIdx.x;
    const int n   = blockIdx.y;
    const int tid = threadIdx.x;
    const int tx  = tid & 15;
    const int ty  = tid >> 4;
    const int i0  = ty * 4;
    const int jrow = tx >> 3;
    const int jx0  = (tx & 7) * 8;

    __shared__ float qS[C_][3][68];
    __shared__ float tS[C_][4][68];
    __shared__ float pnS[HW_];
    __shared__ float qnS[W_];

    const float* sb = s + n * (C_ * HW_);
    const float* tb = t + n * (C_ * HW_);

    for (int jj = tid; jj < HW_; jj += 256) {
        const int y = jj >> 6, x = jj & 63;
        float acc = 0.f;
        for (int c = 0; c < C_; ++c) {
            const float* tc = tb + c * HW_;
            #pragma unroll
            for (int dy = 0; dy < 3; ++dy) {
                const float* tr = tc + iclamp(y + dy - 1, 0, H_ - 1) * W_;
                #pragma unroll
                for (int dx = 0; dx < 3; ++dx) {
                    float v = tr[iclamp(x + dx - 1, 0, W_ - 1)];
                    acc += v * v;
                }
            }
        }
        pnS[jj] = acc;
    }
    for (int idx = tid; idx < C_ * 3 * 66; idx += 256) {
        const int c   = idx / (3 * 66);
        const int rem = idx - c * (3 * 66);
        const int rr  = rem / 66;
        const int xi  = rem - rr * 66;
        qS[c][rr][xi] = sb[c * HW_ + iclamp(yq + rr - 1, 0, H_ - 1) * W_ +
                           iclamp(xi - 1, 0, W_ - 1)];
    }
    __syncthreads();
    if (tid < W_) {
        float acc = 0.f;
        for (int c = 0; c < C_; ++c)
            #pragma unroll
            for (int dy = 0; dy < 3; ++dy)
                #pragma unroll
                for (int dx = 0; dx < 3; ++dx) {
                    float v = qS[c][dy][tid + dx];
                    acc += v * v;
                }
        qnS[tid] = acc;
    }

    unsigned long long best[4] = {~0ull, ~0ull, ~0ull, ~0ull};
    for (int yt = 0; yt < 32; ++yt) {
        __syncthreads();
        for (int idx = tid; idx < C_ * 4 * 66; idx += 256) {
            const int c   = idx / (4 * 66);
            const int rem = idx - c * (4 * 66);
            const int rr  = rem / 66;
            const int xi  = rem - rr * 66;
            tS[c][rr][xi] = tb[c * HW_ + iclamp(2 * yt + rr - 1, 0, H_ - 1) * W_ +
                               iclamp(xi - 1, 0, W_ - 1)];
        }
        __syncthreads();

        float acc[4][8];
        #pragma unroll
        for (int a = 0; a < 4; ++a)
            #pragma unroll
            for (int b = 0; b < 8; ++b) acc[a][b] = 0.f;

        for (int c = 0; c < C_; ++c) {
            #pragma unroll
            for (int dy = 0; dy < 3; ++dy) {
                float qv[8], tv[12];
                *(float4*)&qv[0] = *(const float4*)&qS[c][dy][i0];
                *(float4*)&qv[4] = *(const float4*)&qS[c][dy][i0 + 4];
                const float* trow = &tS[c][jrow + dy][jx0];
                *(float4*)&tv[0] = *(const float4*)&trow[0];
                *(float4*)&tv[4] = *(const float4*)&trow[4];
                *(float4*)&tv[8] = *(const float4*)&trow[8];
                #pragma unroll
                for (int dx = 0; dx < 3; ++dx)
                    #pragma unroll
                    for (int a = 0; a < 4; ++a)
                        #pragma unroll
                        for (int b = 0; b < 8; ++b)
                            acc[a][b] += qv[a + dx] * tv[b + dx];
            }
        }
        const int rbase = (2 * yt + jrow) * W_ + jx0;
        #pragma unroll
        for (int a = 0; a < 4; ++a) {
            const float qn = qnS[i0 + a];
            #pragma unroll
            for (int b = 0; b < 8; ++b) {
                const int j = rbase + b;
                const float d2 = qn + pnS[j] - 2.f * acc[a][b];
                unsigned long long cand =
                    ((unsigned long long)__float_as_uint(d2) << 32) | (unsigned)j;
                best[a] = cand < best[a] ? cand : best[a];
            }
        }
    }
    #pragma unroll
    for (int a = 0; a < 4; ++a) {
        unsigned long long v = best[a];
        #pragma unroll
        for (int mm = 8; mm >= 1; mm >>= 1) {
            unsigned long long o = __shfl_xor(v, mm, 64);
            v = o < v ? o : v;
        }
        best[a] = v;
    }
    if (tx == 0) {
        #pragma unroll
        for (int a = 0; a < 4; ++a) {
            const int x = i0 + a;
            const unsigned j = (unsigned)(best[a] & 0xffffffffu);
            const float d2 = __uint_as_float((unsigned)(best[a] >> 32));
            const int pix = yq * W_ + x;
            out[n * 2 * HW_ + pix]            = (float)(j >> 6);
            out[n * 2 * HW_ + HW_ + pix]      = (float)(j & 63);
            out[N_ * 2 * HW_ + n * HW_ + pix] = d2;
        }
    }
}

// ===========================================================================
extern "C" void kernel_launch(void* const* d_in, const int* in_sizes, int n_in,
                              void* d_out, int out_size, void* d_ws, size_t ws_size,
                              hipStream_t stream) {
    const float* s = (const float*)d_in[0];
    const float* t = (const float*)d_in[1];
    float* out = (float*)d_out;

    // MFMA ws layout:
    //   pn [4][4096] f32 | qn [4][4096] f32 | partial [4][4][4096] u64 |
    //   Qh | Ql | Ph | Pl   each K-major [4][18][4096][8] f16 (4.72 MB)
    const size_t norm_b  = (size_t)N_ * HW_ * 4;
    const size_t part_b  = (size_t)SPLITS_M * N_ * HW_ * 8;
    const size_t desc_b  = (size_t)N_ * HW_ * KK_ * 8 * 2;
    const size_t need_m  = 2 * norm_b + part_b + 4 * desc_b;     // ~19.5 MB

    if (ws_size >= need_m) {
        char* w = (char*)d_ws;
        float* pn = (float*)w;                       w += norm_b;
        float* qn = (float*)w;                       w += norm_b;
        unsigned long long* partial = (unsigned long long*)w; w += part_b;
        f16* Qh = (f16*)w;  w += desc_b;
        f16* Ql = (f16*)w;  w += desc_b;
        f16* Ph = (f16*)w;  w += desc_b;
        f16* Pl = (f16*)w;

        build_desc_norms_kernel<<<dim3(64, N_, 2), 256, 0, stream>>>(
            s, t, Qh, Ql, Ph, Pl, pn, qn);
        mfma_nn_kernel<<<512, 256, 0, stream>>>(Qh, Ql, Ph, Pl, pn, partial);
        finalize_mfma_kernel<<<64, 256, 0, stream>>>(partial, qn, out);
        return;
    }

    // Fallback: fp32 vector path
    const size_t need_v = 2 * norm_b + (size_t)SPLITS_V * N_ * HW_ * 8;
    if (ws_size >= need_v) {
        float* pn = (float*)d_ws;
        float* qn = pn + N_ * HW_;
        unsigned long long* partial =
            (unsigned long long*)((char*)d_ws + 2 * norm_b);
        prep_norms_kernel<<<128, 256, 0, stream>>>(s, t, pn, qn);
        dim3 grid(H_, N_, SPLITS_V);
        patchmatch_main_kernel<<<grid, 256, 0, stream>>>(s, t, pn, qn, partial);
        finalize_kernel<<<64, 256, 0, stream>>>(partial, out);
        return;
    }

    dim3 grid(H_, N_);
    patchmatch_mono_kernel<<<grid, 256, 0, stream>>>(s, t, out);
}

// Round 6
// 133.507 us; speedup vs baseline: 1.0215x; 1.0215x over previous
//
#include <hip/hip_runtime.h>

// PatchMatch brute-force NN on MI355X.
// s,t (4,16,64,64) fp32; descriptor = 3x3 replicate-padded patch, K=144.
// d2(i,j) = qn_i - 2*cross(i,j) + pn_j; argmin_j (ties -> smallest j).
// Outputs (flat, ALL FLOAT32): nnf (4,2,64,64) then nnd (4,1,64,64).
//
// R18 vs R17/R16: R17 (no-LDS global streaming) regressed 60.8->78 (L2 hit
// latency on critical path) -> LDS transport is right. R16 ledger analysis:
// every pipe <45% busy at 8 waves/CU (2/SIMD); VGPR is only 120, so
// occupancy is LDS-bound (77.8KB -> 2 blocks/CU). R18 = R16 compute with
// an LDS diet to raise residency, no register clamp (R14 lesson):
//  - LDS 38.9KB/block: TWO single-tile buffers (2x18KB) + pnS 2KB
//    -> 3-4 blocks/CU (12-16 waves, 3-4/SIMD).
//  - grid 1024 (SPLITS_M 8, j-split 512, 16 single-tile phases) so the
//    extra residency has blocks to run.
//  - per phase: vmcnt(0)+barrier, stage next tile (18 DMAs, {5,5,4,4}
//    per wave), compute 27-MFMA chain; cross-wave overlap covers it.
//  - launch_bounds(256,2): compiler's natural ~140 VGPR, no clamp/spill.

#define N_  4
#define C_  16
#define H_  64
#define W_  64
#define HW_ 4096
#define KK_ 18               // kk blocks of 8 (K=144)
#define SPLITS_M 8           // j-splits; 512 j per split, 16 tiles of 32
#define KKSTRIDE 512         // f16 per kk block in LDS: 32 hi + 32 lo cols x8

#define SPLITS_V 4           // fallback j-splits
#define TILES_PER_SPLIT_V 4

typedef _Float16 f16;
typedef _Float16 f16x8 __attribute__((ext_vector_type(8)));
typedef float    f32x4 __attribute__((ext_vector_type(4)));
typedef float    f32x16 __attribute__((ext_vector_type(16)));

__device__ __forceinline__ int iclamp(int v, int lo, int hi) {
    return v < lo ? lo : (v > hi ? hi : v);
}

__device__ __forceinline__ void async_ld16(const void* g, void* l) {
    __builtin_amdgcn_global_load_lds(
        (const __attribute__((address_space(1))) unsigned int*)g,
        (__attribute__((address_space(3))) unsigned int*)l, 16, 0, 0);
}

// ---------------------------------------------------------------------------
// Kernel 1: K-major fp16 hi/lo descriptors + squared norms.
// D[(n*18 + kk)*4096 + pix][8], kk = k/8, k = d*16 + c (d = dy*3+dx).
// One block per image row; wave q handles kk = q*5..q*5+4 for all 64 px ->
// every store is a 1KB coalesced wavefront store. grid (64, N_, 2).
// ---------------------------------------------------------------------------
__global__ __launch_bounds__(256)
void build_desc_norms_kernel(const float* __restrict__ s,
                             const float* __restrict__ t,
                             f16* __restrict__ Qh, f16* __restrict__ Ql,
                             f16* __restrict__ Ph, f16* __restrict__ Pl,
                             float* __restrict__ pn,
                             float* __restrict__ qn) {
    const int y0  = blockIdx.x;                 // image row
    const int n   = blockIdx.y;
    const int src = blockIdx.z;                 // 0: t, 1: s
    const float* img = (src ? s : t) + n * (C_ * HW_);
    f16* Dh = src ? Qh : Ph;
    f16* Dl = src ? Ql : Pl;
    float* nrm = src ? qn : pn;

    __shared__ float imgS[3][C_][W_];           // 12 KB: rows y0-1..y0+1
    __shared__ float nS[4][W_];
    const int tid = threadIdx.x;
    #pragma unroll
    for (int k = 0; k < 12; ++k) {
        const int idx = tid + k * 256;          // 0..3071
        const int x = idx & 63, c = (idx >> 6) & 15, r = idx >> 10;  // r 0..2
        const int gy = iclamp(y0 + r - 1, 0, H_ - 1);
        imgS[r][c][x] = img[c * HW_ + gy * W_ + x];
    }
    __syncthreads();

    const int q = tid >> 6, x = tid & 63;       // wave, lane(=pixel x)
    const int pix = y0 * W_ + x;
    float nacc = 0.f;
    #pragma unroll
    for (int u = 0; u < 5; ++u) {
        const int kk = q * 5 + u;               // 0..19
        if (kk < KK_) {
            f16x8 hv, lv;
            const int d  = kk >> 1;             // 0..8
            const int c0 = (kk & 1) * 8;
            const int dy = (d * 11) >> 5;       // d/3 for d in [0,8]
            const int dx = d - dy * 3;
            const int xs = iclamp(x + dx - 1, 0, W_ - 1);
            #pragma unroll
            for (int cc = 0; cc < 8; ++cc) {
                const float v = imgS[dy][c0 + cc][xs];
                const f16 h = (f16)v;
                hv[cc] = h;
                lv[cc] = (f16)(v - (float)h);
                nacc += v * v;
            }
            const size_t off = ((size_t)(n * KK_ + kk) * HW_ + pix) * 8;
            *(f16x8*)&Dh[off] = hv;             // 64 lanes x 16B contiguous
            *(f16x8*)&Dl[off] = lv;
        }
    }
    nS[q][x] = nacc;
    __syncthreads();
    if (tid < W_)
        nrm[n * HW_ + pix] = nS[0][tid] + nS[1][tid] + nS[2][tid] + nS[3][tid];
}

// ---------------------------------------------------------------------------
// Kernel 2: MFMA GEMM + fused argmax. 1D grid 1024 (split=bid&7, XCD-pinned
// under round-robin); block = 4 waves, wave = one 32-row output stripe.
// j: 512 per split = 16 single-tile phases; DOUBLE-buffered LDS (2x18KB);
// per phase: vmcnt(0)+s_barrier (drains DMAs issued a full phase earlier),
// stage next tile (18 DMAs, {5,5,4,4}/wave), 27-MFMA chain from other buf.
// LDS buffer: [kk 0..17][h(32 cols)|l(32 cols)][8 f16], KKSTRIDE=512.
// mfma_f32_32x32x16_f16: A/B [idx=lane&31][k=(lane>>5)*8+e];
// C col=lane&31, row=(reg&3)+8*(reg>>2)+4*(lane>>5).
// Cf initialized to -pn_j/2: argmin d2 == argmax Cf; partial stores -2*Cf.
// ---------------------------------------------------------------------------
__global__ __launch_bounds__(256, 2)
void mfma_nn_kernel(const f16* __restrict__ Qh, const f16* __restrict__ Ql,
                    const f16* __restrict__ Ph, const f16* __restrict__ Pl,
                    const float* __restrict__ pn_g,
                    unsigned long long* __restrict__ partial) {
    const int bid   = blockIdx.x;
    const int split = bid & 7;          // XCD affinity under round-robin
    const int n     = (bid >> 3) & 3;
    const int iblk  = bid >> 5;         // 0..31
    const int tid  = threadIdx.x;
    const int wave = tid >> 6, lane = tid & 63;
    const int col  = lane & 31;         // A row / B col / C col
    const int half = lane >> 5;         // k-half within a 16-chunk
    const int irow0 = iblk * 128 + wave * 32;

    __shared__ f16 B0[KK_ * KKSTRIDE];  // 18432 B
    __shared__ f16 B1[KK_ * KKSTRIDE];  // 18432 B
    __shared__ float pnS[512];          // this split's pn (2 KB)

    // ---- A fragments, resident (72 VGPR): 9 chunks of K=16 ----
    f16x8 Ah[9], Al[9];
    #pragma unroll
    for (int c = 0; c < 9; ++c) {
        const size_t off = ((size_t)(n * KK_ + 2 * c + half) * HW_ +
                            irow0 + col) * 8;
        Ah[c] = *(const f16x8*)(Qh + off);
        Al[c] = *(const f16x8*)(Ql + off);
    }

    const int jsplit0 = split * 512;
    pnS[tid]       = pn_g[n * HW_ + jsplit0 + tid];
    if (tid < 256) pnS[tid + 256] = pn_g[n * HW_ + jsplit0 + tid + 256];

    float    bd[16];
    unsigned bj[16];
    #pragma unroll
    for (int r = 0; r < 16; ++r) { bd[r] = -3.0e38f; bj[r] = 0u; }

    // staging: 18 kk rows split {5,5,4,4} across the 4 waves
    const int nst = (wave < 2) ? 5 : 4;
    const int kk0 = (wave < 2) ? wave * 5 : 10 + (wave - 2) * 4;
    const f16* sbase = half ? Pl : Ph;  // lanes 0-31: hi rows, 32-63: lo rows

    #define STAGE(BUF, T)                                                     \
        {   _Pragma("unroll")                                                 \
            for (int u = 0; u < 5; ++u) {                                     \
                if (u < nst) {                                                \
                    const int kk = kk0 + u;                                   \
                    const f16* g = sbase + ((size_t)(n * KK_ + kk) * HW_ +    \
                                            jsplit0 + (T) * 32 + col) * 8;    \
                    async_ld16(g, (void*)&BUF[kk * KKSTRIDE + lane * 8]);     \
                }                                                             \
            }                                                                 \
        }

    #define BAR()                                                             \
        {   asm volatile("s_waitcnt vmcnt(0)" ::: "memory");                  \
            asm volatile("s_barrier" ::: "memory");                           \
        }

    #define COMPUTE(BUF, T)                                                   \
        {   const int jloc = (T) * 32 + col;                                  \
            const float pnv = -0.5f * pnS[jloc];                              \
            f32x16 Cf;                                                        \
            _Pragma("unroll")                                                 \
            for (int r = 0; r < 16; ++r) Cf[r] = pnv;                         \
            __builtin_amdgcn_s_setprio(1);                                    \
            _Pragma("unroll")                                                 \
            for (int c = 0; c < 9; ++c) {                                     \
                const int kb = (2 * c + half) * KKSTRIDE + col * 8;           \
                const f16x8 bh = *(const f16x8*)&BUF[kb];                     \
                const f16x8 bl = *(const f16x8*)&BUF[kb + 256];               \
                Cf = __builtin_amdgcn_mfma_f32_32x32x16_f16(                  \
                    Ah[c], bh, Cf, 0, 0, 0);                                  \
                Cf = __builtin_amdgcn_mfma_f32_32x32x16_f16(                  \
                    Al[c], bh, Cf, 0, 0, 0);                                  \
                Cf = __builtin_amdgcn_mfma_f32_32x32x16_f16(                  \
                    Ah[c], bl, Cf, 0, 0, 0);                                  \
            }                                                                 \
            __builtin_amdgcn_s_setprio(0);                                    \
            _Pragma("unroll")                                                 \
            for (int r = 0; r < 16; ++r)                                      \
                if (Cf[r] > bd[r]) { bd[r] = Cf[r]; bj[r] = (unsigned)jloc; } \
        }

    STAGE(B0, 0)
    asm volatile("s_waitcnt vmcnt(0)" ::: "memory");
    __syncthreads();                    // pnS + tile 0 visible

    STAGE(B1, 1)  COMPUTE(B0, 0)       // phase 0
    for (int g = 0; g < 7; ++g) {      // phases 1..14
        const int t2 = g * 2;
        BAR()  STAGE(B0, t2 + 2)  COMPUTE(B1, t2 + 1)
        BAR()  STAGE(B1, t2 + 3)  COMPUTE(B0, t2 + 2)
    }
    BAR()  COMPUTE(B1, 15)             // phase 15
    #undef STAGE
    #undef BAR
    #undef COMPUTE

    // ---- argmax reduce across the 32 cols (lanes col=0..31 per half) ----
    #pragma unroll
    for (int r = 0; r < 16; ++r) {
        float    d = bd[r];
        unsigned j = (unsigned)jsplit0 + bj[r];
        #pragma unroll
        for (int off = 1; off < 32; off <<= 1) {
            const float    od = __shfl_xor(d, off, 64);
            const unsigned oj = __shfl_xor(j, off, 64);
            const bool take = (od > d) || (od == d && oj < j);
            d = take ? od : d;
            j = take ? oj : j;
        }
        if (col == 0) {
            const int i = irow0 + (r & 3) + 8 * (r >> 2) + 4 * half;
            partial[(size_t)(split * N_ + n) * HW_ + i] =
                ((unsigned long long)j << 32) |
                (unsigned long long)__float_as_uint(-2.f * d);
        }
    }
}

// ---------------------------------------------------------------------------
// Kernel 3: reduce splits, add qn, decode, write outputs (float32)
// ---------------------------------------------------------------------------
__global__ __launch_bounds__(256)
void finalize_mfma_kernel(const unsigned long long* __restrict__ partial,
                          const float* __restrict__ qn_g,
                          float* __restrict__ out) {
    const int id  = blockIdx.x * 256 + threadIdx.x;   // 0..16383
    const int n   = id >> 12;
    const int pix = id & 4095;
    float    bd = 3.0e38f;
    unsigned bj = 0u;
    #pragma unroll
    for (int sp = 0; sp < SPLITS_M; ++sp) {
        const unsigned long long v = partial[(size_t)(sp * N_ + n) * HW_ + pix];
        const float    d = __uint_as_float((unsigned)(v & 0xffffffffull));
        const unsigned j = (unsigned)(v >> 32);
        const bool take = (d < bd) || (d == bd && j < bj);
        bd = take ? d : bd;
        bj = take ? j : bj;
    }
    out[n * 2 * HW_ + pix]            = (float)(bj >> 6);          // idy
    out[n * 2 * HW_ + HW_ + pix]      = (float)(bj & 63);          // idx_x
    out[N_ * 2 * HW_ + n * HW_ + pix] = bd + qn_g[n * HW_ + pix];  // nnd
}

// ===========================================================================
// Fallback path (fp32 vector) + helpers — unchanged
// ===========================================================================
__global__ __launch_bounds__(256)
void prep_norms_kernel(const float* __restrict__ s,
                       const float* __restrict__ t,
                       float* __restrict__ pn,
                       float* __restrict__ qn) {
    const int gid   = blockIdx.x * 256 + threadIdx.x;
    const int which = gid >> 14;
    const int id    = gid & 16383;
    const int n     = id >> 12;
    const int pix   = id & 4095;
    const int y = pix >> 6, x = pix & 63;
    const float* base = (which ? s : t) + n * (C_ * HW_);
    float acc = 0.f;
    for (int c = 0; c < C_; ++c) {
        const float* bc = base + c * HW_;
        #pragma unroll
        for (int dy = 0; dy < 3; ++dy) {
            const float* br = bc + iclamp(y + dy - 1, 0, H_ - 1) * W_;
            #pragma unroll
            for (int dx = 0; dx < 3; ++dx) {
                float v = br[iclamp(x + dx - 1, 0, W_ - 1)];
                acc += v * v;
            }
        }
    }
    (which ? qn : pn)[id] = acc;
}

__global__ __launch_bounds__(256)
void patchmatch_main_kernel(const float* __restrict__ s,
                            const float* __restrict__ t,
                            const float* __restrict__ pn_g,
                            const float* __restrict__ qn_g,
                            unsigned long long* __restrict__ partial) {
    const int yq    = blockIdx.x;
    const int n     = blockIdx.y;
    const int split = blockIdx.z;
    const int tid  = threadIdx.x;
    const int tx   = tid & 15;
    const int ty   = tid >> 4;
    const int i0   = ty * 4;
    const int jrow = tx >> 2;
    const int jx0  = (tx & 3) * 16;

    __shared__ float qS[C_][3][68];
    __shared__ float tS[C_][6][68];
    __shared__ float qnS[W_];

    const float* sb = s + n * (C_ * HW_);
    const float* tb = t + n * (C_ * HW_);

    #pragma unroll
    for (int k = 0; k < 3; ++k) {
        const int id = tid + k * 256;
        const int sg = id & 15;
        const int c  = (id >> 4) & 15;
        const int r  = id >> 8;
        const int gr = iclamp(yq + r - 1, 0, H_ - 1);
        const float4 v = *(const float4*)&sb[c * HW_ + gr * W_ + sg * 4];
        float* dst = &qS[c][r][1 + sg * 4];
        dst[0] = v.x; dst[1] = v.y; dst[2] = v.z; dst[3] = v.w;
    }
    if (tid < 48) {
        const int c  = tid & 15;
        const int r  = tid >> 4;
        const int gr = iclamp(yq + r - 1, 0, H_ - 1);
        qS[c][r][0]  = sb[c * HW_ + gr * W_];
        qS[c][r][65] = sb[c * HW_ + gr * W_ + 63];
    }
    if (tid < W_) qnS[tid] = qn_g[n * HW_ + yq * W_ + tid];

    unsigned long long best[4] = {~0ull, ~0ull, ~0ull, ~0ull};

    for (int ytl = 0; ytl < TILES_PER_SPLIT_V; ++ytl) {
        const int yt = split * TILES_PER_SPLIT_V + ytl;
        __syncthreads();
        #pragma unroll
        for (int k = 0; k < 6; ++k) {
            const int id = tid + k * 256;
            const int sg = id & 15;
            const int c  = (id >> 4) & 15;
            const int r  = id >> 8;
            const int gr = iclamp(4 * yt + r - 1, 0, H_ - 1);
            const float4 v = *(const float4*)&tb[c * HW_ + gr * W_ + sg * 4];
            float* dst = &tS[c][r][1 + sg * 4];
            dst[0] = v.x; dst[1] = v.y; dst[2] = v.z; dst[3] = v.w;
        }
        if (tid < 96) {
            const int c  = tid & 15;
            const int r  = tid >> 4;
            const int gr = iclamp(4 * yt + r - 1, 0, H_ - 1);
            tS[c][r][0]  = tb[c * HW_ + gr * W_];
            tS[c][r][65] = tb[c * HW_ + gr * W_ + 63];
        }
        __syncthreads();

        float acc[4][16];
        #pragma unroll
        for (int a = 0; a < 4; ++a)
            #pragma unroll
            for (int b = 0; b < 16; ++b) acc[a][b] = 0.f;

        for (int c = 0; c < C_; ++c) {
            #pragma unroll
            for (int dy = 0; dy < 3; ++dy) {
                float qv[6], tv[18];
                *(float4*)&qv[0] = *(const float4*)&qS[c][dy][i0];
                *(float2*)&qv[4] = *(const float2*)&qS[c][dy][i0 + 4];
                const float* trow = &tS[c][jrow + dy][jx0];
                *(float4*)&tv[0]  = *(const float4*)&trow[0];
                *(float4*)&tv[4]  = *(const float4*)&trow[4];
                *(float4*)&tv[8]  = *(const float4*)&trow[8];
                *(float4*)&tv[12] = *(const float4*)&trow[12];
                *(float2*)&tv[16] = *(const float2*)&trow[16];
                #pragma unroll
                for (int dx = 0; dx < 3; ++dx)
                    #pragma unroll
                    for (int a = 0; a < 4; ++a)
                        #pragma unroll
                        for (int b = 0; b < 16; ++b)
                            acc[a][b] += qv[a + dx] * tv[b + dx];
            }
        }

        const int jbase = yt * 256 + jrow * W_ + jx0;
        float pnv[16];
        const float* png = &pn_g[n * HW_ + jbase];
        *(float4*)&pnv[0]  = *(const float4*)&png[0];
        *(float4*)&pnv[4]  = *(const float4*)&png[4];
        *(float4*)&pnv[8]  = *(const float4*)&png[8];
        *(float4*)&pnv[12] = *(const float4*)&png[12];
        #pragma unroll
        for (int a = 0; a < 4; ++a) {
            const float qn = qnS[i0 + a];
            #pragma unroll
            for (int b = 0; b < 16; ++b) {
                const float d2 = qn + pnv[b] - 2.f * acc[a][b];
                unsigned long long cand =
                    ((unsigned long long)__float_as_uint(d2) << 32) |
                    (unsigned)(jbase + b);
                best[a] = cand < best[a] ? cand : best[a];
            }
        }
    }

    #pragma unroll
    for (int a = 0; a < 4; ++a) {
        unsigned long long v = best[a];
        #pragma unroll
        for (int mm = 8; mm >= 1; mm >>= 1) {
            unsigned long long o = __shfl_xor(v, mm, 64);
            v = o < v ? o : v;
        }
        best[a] = v;
    }
    if (tx == 0) {
        #pragma unroll
        for (int a = 0; a < 4; ++a)
            partial[((split * N_ + n) * HW_) + yq * W_ + i0 + a] = best[a];
    }
}

__global__ __launch_bounds__(256)
void finalize_kernel(const unsigned long long* __restrict__ partial,
                     float* __restrict__ out) {
    const int id  = blockIdx.x * 256 + threadIdx.x;
    const int n   = id >> 12;
    const int pix = id & 4095;
    unsigned long long best = ~0ull;
    #pragma unroll
    for (int sp = 0; sp < SPLITS_V; ++sp) {
        unsigned long long v = partial[(sp * N_ + n) * HW_ + pix];
        best = v < best ? v : best;
    }
    const unsigned j = (unsigned)(best & 0xffffffffu);
    const float d2 = __uint_as_float((unsigned)(best >> 32));
    out[n * 2 * HW_ + pix]            = (float)(j >> 6);
    out[n * 2 * HW_ + HW_ + pix]      = (float)(j & 63);
    out[N_ * 2 * HW_ + n * HW_ + pix] = d2;
}

__global__ __launch_bounds__(256)
void patchmatch_mono_kernel(const float* __restrict__ s,
                            const float* __restrict__ t,
                            float* __restrict__ out) {
    const int yq  = blockIdx.x;
    const int n   = blockIdx.y;
    const int tid = threadIdx.x;
    const int tx  = tid & 15;
    const int ty  = tid >> 4;
    const int i0  = ty * 4;
    const int jrow = tx >> 3;
    const int jx0  = (tx & 7) * 8;

    __shared__ float qS[C_][3][68];
    __shared__ float tS[C_][4][68];
    __shared__ float pnS[HW_];
    __shared__ float qnS[W_];

    const float* sb = s + n * (C_ * HW_);
    const float* tb = t + n * (C_ * HW_);

    for (int jj = tid; jj < HW_; jj += 256) {
        const int y = jj >> 6, x = jj & 63;
        float acc = 0.f;
        for (int c = 0; c < C_; ++c) {
            const float* tc = tb + c * HW_;
            #pragma unroll
            for (int dy = 0; dy < 3; ++dy) {
                const float* tr = tc + iclamp(y + dy - 1, 0, H_ - 1) * W_;
                #pragma unroll
                for (int dx = 0; dx < 3; ++dx) {
                    float v = tr[iclamp(x + dx - 1, 0, W_ - 1)];
                    acc += v * v;
                }
            }
        }
        pnS[jj] = acc;
    }
    for (int idx = tid; idx < C_ * 3 * 66; idx += 256) {
        const int c   = idx / (3 * 66);
        const int rem = idx - c * (3 * 66);
        const int rr  = rem / 66;
        const int xi  = rem - rr * 66;
        qS[c][rr][xi] = sb[c * HW_ + iclamp(yq + rr - 1, 0, H_ - 1) * W_ +
                           iclamp(xi - 1, 0, W_ - 1)];
    }
    __syncthreads();
    if (tid < W_) {
        float acc = 0.f;
        for (int c = 0; c < C_; ++c)
            #pragma unroll
            for (int dy = 0; dy < 3; ++dy)
                #pragma unroll
                for (int dx = 0; dx < 3; ++dx) {
                    float v = qS[c][dy][tid + dx];
                    acc += v * v;
                }
        qnS[tid] = acc;
    }

    unsigned long long best[4] = {~0ull, ~0ull, ~0ull, ~0ull};
    for (int yt = 0; yt < 32; ++yt) {
        __syncthreads();
        for (int idx = tid; idx < C_ * 4 * 66; idx += 256) {
            const int c   = idx / (4 * 66);
            const int rem = idx - c * (4 * 66);
            const int rr  = rem / 66;
            const int xi  = rem - rr * 66;
            tS[c][rr][xi] = tb[c * HW_ + iclamp(2 * yt + rr - 1, 0, H_ - 1) * W_ +
                               iclamp(xi - 1, 0, W_ - 1)];
        }
        __syncthreads();

        float acc[4][8];
        #pragma unroll
        for (int a = 0; a < 4; ++a)
            #pragma unroll
            for (int b = 0; b < 8; ++b) acc[a][b] = 0.f;

        for (int c = 0; c < C_; ++c) {
            #pragma unroll
            for (int dy = 0; dy < 3; ++dy) {
                float qv[8], tv[12];
                *(float4*)&qv[0] = *(const float4*)&qS[c][dy][i0];
                *(float4*)&qv[4] = *(const float4*)&qS[c][dy][i0 + 4];
                const float* trow = &tS[c][jrow + dy][jx0];
                *(float4*)&tv[0] = *(const float4*)&trow[0];
                *(float4*)&tv[4] = *(const float4*)&trow[4];
                *(float4*)&tv[8] = *(const float4*)&trow[8];
                #pragma unroll
                for (int dx = 0; dx < 3; ++dx)
                    #pragma unroll
                    for (int a = 0; a < 4; ++a)
                        #pragma unroll
                        for (int b = 0; b < 8; ++b)
                            acc[a][b] += qv[a + dx] * tv[b + dx];
            }
        }
        const int rbase = (2 * yt + jrow) * W_ + jx0;
        #pragma unroll
        for (int a = 0; a < 4; ++a) {
            const float qn = qnS[i0 + a];
            #pragma unroll
            for (int b = 0; b < 8; ++b) {
                const int j = rbase + b;
                const float d2 = qn + pnS[j] - 2.f * acc[a][b];
                unsigned long long cand =
                    ((unsigned long long)__float_as_uint(d2) << 32) | (unsigned)j;
                best[a] = cand < best[a] ? cand : best[a];
            }
        }
    }
    #pragma unroll
    for (int a = 0; a < 4; ++a) {
        unsigned long long v = best[a];
        #pragma unroll
        for (int mm = 8; mm >= 1; mm >>= 1) {
            unsigned long long o = __shfl_xor(v, mm, 64);
            v = o < v ? o : v;
        }
        best[a] = v;
    }
    if (tx == 0) {
        #pragma unroll
        for (int a = 0; a < 4; ++a) {
            const int x = i0 + a;
            const unsigned j = (unsigned)(best[a] & 0xffffffffu);
            const float d2 = __uint_as_float((unsigned)(best[a] >> 32));
            const int pix = yq * W_ + x;
            out[n * 2 * HW_ + pix]            = (float)(j >> 6);
            out[n * 2 * HW_ + HW_ + pix]      = (float)(j & 63);
            out[N_ * 2 * HW_ + n * HW_ + pix] = d2;
        }
    }
}

// ===========================================================================
extern "C" void kernel_launch(void* const* d_in, const int* in_sizes, int n_in,
                              void* d_out, int out_size, void* d_ws, size_t ws_size,
                              hipStream_t stream) {
    const float* s = (const float*)d_in[0];
    const float* t = (const float*)d_in[1];
    float* out = (float*)d_out;

    // MFMA ws layout:
    //   pn [4][4096] f32 | qn [4][4096] f32 | partial [8][4][4096] u64 |
    //   Qh | Ql | Ph | Pl   each K-major [4][18][4096][8] f16 (4.72 MB)
    const size_t norm_b  = (size_t)N_ * HW_ * 4;
    const size_t part_b  = (size_t)SPLITS_M * N_ * HW_ * 8;
    const size_t desc_b  = (size_t)N_ * HW_ * KK_ * 8 * 2;
    const size_t need_m  = 2 * norm_b + part_b + 4 * desc_b;     // ~20.1 MB

    if (ws_size >= need_m) {
        char* w = (char*)d_ws;
        float* pn = (float*)w;                       w += norm_b;
        float* qn = (float*)w;                       w += norm_b;
        unsigned long long* partial = (unsigned long long*)w; w += part_b;
        f16* Qh = (f16*)w;  w += desc_b;
        f16* Ql = (f16*)w;  w += desc_b;
        f16* Ph = (f16*)w;  w += desc_b;
        f16* Pl = (f16*)w;

        build_desc_norms_kernel<<<dim3(64, N_, 2), 256, 0, stream>>>(
            s, t, Qh, Ql, Ph, Pl, pn, qn);
        mfma_nn_kernel<<<1024, 256, 0, stream>>>(Qh, Ql, Ph, Pl, pn, partial);
        finalize_mfma_kernel<<<64, 256, 0, stream>>>(partial, qn, out);
        return;
    }

    // Fallback: fp32 vector path
    const size_t need_v = 2 * norm_b + (size_t)SPLITS_V * N_ * HW_ * 8;
    if (ws_size >= need_v) {
        float* pn = (float*)d_ws;
        float* qn = pn + N_ * HW_;
        unsigned long long* partial =
            (unsigned long long*)((char*)d_ws + 2 * norm_b);
        prep_norms_kernel<<<128, 256, 0, stream>>>(s, t, pn, qn);
        dim3 grid(H_, N_, SPLITS_V);
        patchmatch_main_kernel<<<grid, 256, 0, stream>>>(s, t, pn, qn, partial);
        finalize_kernel<<<64, 256, 0, stream>>>(partial, out);
        return;
    }

    dim3 grid(H_, N_);
    patchmatch_mono_kernel<<<grid, 256, 0, stream>>>(s, t, out);
}

// Round 7
// 125.629 us; speedup vs baseline: 1.0855x; 1.0627x over previous
//
#include <hip/hip_runtime.h>
#include <hip/hip_cooperative_groups.h>

// PatchMatch brute-force NN on MI355X.
// s,t (4,16,64,64) fp32; descriptor = 3x3 replicate-padded patch, K=144.
// d2(i,j) = qn_i - 2*cross(i,j) + pn_j; argmin_j (ties -> smallest j).
// Outputs (flat, ALL FLOAT32): nnf (4,2,64,64) then nnd (4,1,64,64).
//
// R19 vs R18/R16: occupancy thesis falsified (R18: LDS 39KB + VGPR 88 still
// ~21% occ, dur regressed) -> mfma structure stays R16 (best, 60.8us).
// New target: total - mfma = 63.5us CONSTANT across all rounds = build_desc
// (scalar loads) + finalize + two inter-kernel gaps. R19 fuses the whole
// pipeline into ONE cooperative kernel (grid 512 = exactly 2 blocks/CU
// co-resident), grid.sync() between phases:
//  - phase 1: build descriptors+norms (float4 image loads, was 12 scalar).
//  - phase 2: R16 mfma GEMM+argmax VERBATIM (pairs of tiles, vmcnt(0)+bar).
//  - phase 3: inline finalize (split-reduce, decode, write out).
//  - LDS phases overlay in the same 77.8KB; threadfence around grid.sync.
//  - occupancy-query guard + clean fallback to the 3-kernel path.

#define N_  4
#define C_  16
#define H_  64
#define W_  64
#define HW_ 4096
#define KK_ 18               // kk blocks of 8 (K=144)
#define SPLITS_M 4           // j-splits; 1024 j per split, 32 tiles of 32
#define KKSTRIDE 512         // f16 per kk block in LDS: 32 hi + 32 lo cols x8

#define SPLITS_V 4           // fallback j-splits
#define TILES_PER_SPLIT_V 4

typedef _Float16 f16;
typedef _Float16 f16x8 __attribute__((ext_vector_type(8)));
typedef float    f32x4 __attribute__((ext_vector_type(4)));
typedef float    f32x16 __attribute__((ext_vector_type(16)));

namespace cg = cooperative_groups;

__device__ __forceinline__ int iclamp(int v, int lo, int hi) {
    return v < lo ? lo : (v > hi ? hi : v);
}

__device__ __forceinline__ void async_ld16(const void* g, void* l) {
    __builtin_amdgcn_global_load_lds(
        (const __attribute__((address_space(1))) unsigned int*)g,
        (__attribute__((address_space(3))) unsigned int*)l, 16, 0, 0);
}

// ===========================================================================
// Fused cooperative kernel: build -> grid.sync -> mfma -> grid.sync -> final
// grid 512 x 256 threads; LDS 77.8KB -> exactly 2 blocks/CU co-resident.
// ===========================================================================
__global__ __launch_bounds__(256, 2)
void fused_nn_kernel(const float* __restrict__ s, const float* __restrict__ t,
                     f16* __restrict__ Qh, f16* __restrict__ Ql,
                     f16* __restrict__ Ph, f16* __restrict__ Pl,
                     float* __restrict__ pn, float* __restrict__ qn,
                     unsigned long long* __restrict__ partial,
                     float* __restrict__ out) {
    cg::grid_group grid = cg::this_grid();

    __shared__ __align__(16) f16 Bbuf[4][KK_ * KKSTRIDE]; // 73.7KB
    __shared__ float pnS[1024];                           // 4KB

    const int bid = blockIdx.x;
    const int tid = threadIdx.x;

    // ---------------- Phase 1: descriptors + norms -----------------------
    {
        const int y0  = bid & 63;
        const int n   = (bid >> 6) & 3;
        const int src = bid >> 8;                   // 0: t, 1: s
        const float* img = (src ? s : t) + n * (C_ * HW_);
        f16* Dh = src ? Qh : Ph;
        f16* Dl = src ? Ql : Pl;
        float* nrm = src ? qn : pn;

        float (*imgS)[C_][W_] = (float (*)[C_][W_]) & Bbuf[0][0]; // 12KB
        float (*nS)[W_] = (float (*)[W_])((char*)&Bbuf[0][0] + 12288);

        #pragma unroll
        for (int k = 0; k < 3; ++k) {               // 768 float4 loads
            const int i4 = tid + k * 256;
            const int x4 = i4 & 15, c = (i4 >> 4) & 15, r = i4 >> 8; // r 0..2
            const int gy = iclamp(y0 + r - 1, 0, H_ - 1);
            const float4 v = *(const float4*)&img[c * HW_ + gy * W_ + x4 * 4];
            *(float4*)&imgS[r][c][x4 * 4] = v;
        }
        __syncthreads();

        const int q = tid >> 6, x = tid & 63;       // wave, lane(=pixel x)
        const int pix = y0 * W_ + x;
        float nacc = 0.f;
        #pragma unroll
        for (int u = 0; u < 5; ++u) {
            const int kk = q * 5 + u;               // 0..19
            if (kk < KK_) {
                f16x8 hv, lv;
                const int d  = kk >> 1;             // 0..8
                const int c0 = (kk & 1) * 8;
                const int dy = (d * 11) >> 5;       // d/3 for d in [0,8]
                const int dx = d - dy * 3;
                const int xs = iclamp(x + dx - 1, 0, W_ - 1);
                #pragma unroll
                for (int cc = 0; cc < 8; ++cc) {
                    const float v = imgS[dy][c0 + cc][xs];
                    const f16 h = (f16)v;
                    hv[cc] = h;
                    lv[cc] = (f16)(v - (float)h);
                    nacc += v * v;
                }
                const size_t off = ((size_t)(n * KK_ + kk) * HW_ + pix) * 8;
                *(f16x8*)&Dh[off] = hv;             // 1KB wavefront store
                *(f16x8*)&Dl[off] = lv;
            }
        }
        nS[q][x] = nacc;
        __syncthreads();
        if (tid < W_)
            nrm[n * HW_ + pix] =
                nS[0][tid] + nS[1][tid] + nS[2][tid] + nS[3][tid];
    }

    __threadfence();        // device-scope release of descriptors/norms
    grid.sync();
    __threadfence();        // acquire side

    // ---------------- Phase 2: MFMA GEMM + argmax (R16 verbatim) ---------
    {
        const int split = bid & 3;          // XCD affinity under round-robin
        const int n     = (bid >> 2) & 3;
        const int iblk  = bid >> 4;         // 0..31
        const int wave = tid >> 6, lane = tid & 63;
        const int col  = lane & 31;         // A row / B col / C col
        const int half = lane >> 5;         // k-half within a 16-chunk
        const int irow0 = iblk * 128 + wave * 32;

        // ---- A fragments, resident (72 VGPR): 9 chunks of K=16 ----
        f16x8 Ah[9], Al[9];
        #pragma unroll
        for (int c = 0; c < 9; ++c) {
            const size_t off = ((size_t)(n * KK_ + 2 * c + half) * HW_ +
                                irow0 + col) * 8;
            Ah[c] = *(const f16x8*)(Qh + off);
            Al[c] = *(const f16x8*)(Ql + off);
        }

        const int jsplit0 = split * 1024;
        #pragma unroll
        for (int k = 0; k < 4; ++k)
            pnS[tid + k * 256] = pn[n * HW_ + jsplit0 + tid + k * 256];

        float    bd[16];
        unsigned bj[16];
        #pragma unroll
        for (int r = 0; r < 16; ++r) { bd[r] = -3.0e38f; bj[r] = 0u; }

        // staging: 2 tiles x 18 kk rows = 36 DMAs, 9 per wave (uniform).
        const int stile = wave >> 1;
        const int skk0  = (wave & 1) * 9;
        const f16* sbase = half ? Pl : Ph;

        #define STAGE(PAIR, T0)                                               \
            {   _Pragma("unroll")                                             \
                for (int u = 0; u < 9; ++u) {                                 \
                    const int kk = skk0 + u;                                  \
                    const f16* g = sbase + ((size_t)(n * KK_ + kk) * HW_ +    \
                                            jsplit0 + ((T0) + stile) * 32 +   \
                                            col) * 8;                         \
                    async_ld16(g, (void*)&Bbuf[(PAIR) * 2 + stile]            \
                                              [kk * KKSTRIDE + lane * 8]);    \
                }                                                             \
            }

        #define BAR()                                                         \
            {   asm volatile("s_waitcnt vmcnt(0)" ::: "memory");              \
                asm volatile("s_barrier" ::: "memory");                       \
            }

        #define COMPUTE2(PAIR, T0)                                            \
            {   const int j0 = (T0) * 32 + col;                               \
                const float pnv0 = -0.5f * pnS[j0];                           \
                const float pnv1 = -0.5f * pnS[j0 + 32];                      \
                f32x16 C0, C1;                                                \
                _Pragma("unroll")                                             \
                for (int r = 0; r < 16; ++r) { C0[r] = pnv0; C1[r] = pnv1; }  \
                __builtin_amdgcn_s_setprio(1);                                \
                _Pragma("unroll")                                             \
                for (int c = 0; c < 9; ++c) {                                 \
                    const int kb = (2 * c + half) * KKSTRIDE + col * 8;       \
                    const f16x8 bh0 = *(const f16x8*)&Bbuf[(PAIR) * 2][kb];   \
                    const f16x8 bl0 = *(const f16x8*)&Bbuf[(PAIR) * 2]        \
                                                          [kb + 256];         \
                    const f16x8 bh1 = *(const f16x8*)&Bbuf[(PAIR) * 2 + 1]    \
                                                          [kb];               \
                    const f16x8 bl1 = *(const f16x8*)&Bbuf[(PAIR) * 2 + 1]    \
                                                          [kb + 256];         \
                    C0 = __builtin_amdgcn_mfma_f32_32x32x16_f16(              \
                        Ah[c], bh0, C0, 0, 0, 0);                             \
                    C1 = __builtin_amdgcn_mfma_f32_32x32x16_f16(              \
                        Ah[c], bh1, C1, 0, 0, 0);                             \
                    C0 = __builtin_amdgcn_mfma_f32_32x32x16_f16(              \
                        Al[c], bh0, C0, 0, 0, 0);                             \
                    C1 = __builtin_amdgcn_mfma_f32_32x32x16_f16(              \
                        Al[c], bh1, C1, 0, 0, 0);                             \
                    C0 = __builtin_amdgcn_mfma_f32_32x32x16_f16(              \
                        Ah[c], bl0, C0, 0, 0, 0);                             \
                    C1 = __builtin_amdgcn_mfma_f32_32x32x16_f16(              \
                        Ah[c], bl1, C1, 0, 0, 0);                             \
                }                                                             \
                __builtin_amdgcn_s_setprio(0);                                \
                _Pragma("unroll")                                             \
                for (int r = 0; r < 16; ++r) {                                \
                    if (C0[r] > bd[r]) { bd[r] = C0[r];                       \
                                         bj[r] = (unsigned)j0; }              \
                    if (C1[r] > bd[r]) { bd[r] = C1[r];                       \
                                         bj[r] = (unsigned)(j0 + 32); }       \
                }                                                             \
            }

        STAGE(0, 0)                        // tiles 0,1 -> pair 0
        asm volatile("s_waitcnt vmcnt(0)" ::: "memory");
        __syncthreads();                   // pnS + pair 0 visible

        STAGE(1, 2)  COMPUTE2(0, 0)        // phase 0
        for (int gg = 0; gg < 6; ++gg) {   // phases 1..12
            const int t4 = gg * 4;
            BAR()  STAGE(0, t4 + 4)  COMPUTE2(1, t4 + 2)
            BAR()  STAGE(1, t4 + 6)  COMPUTE2(0, t4 + 4)
        }
        BAR()  STAGE(0, 28)  COMPUTE2(1, 26)   // phase 13
        BAR()  STAGE(1, 30)  COMPUTE2(0, 28)   // phase 14
        BAR()               COMPUTE2(1, 30)    // phase 15
        #undef STAGE
        #undef BAR
        #undef COMPUTE2

        // ---- argmax reduce across the 32 cols ----
        #pragma unroll
        for (int r = 0; r < 16; ++r) {
            float    d = bd[r];
            unsigned j = (unsigned)jsplit0 + bj[r];
            #pragma unroll
            for (int off = 1; off < 32; off <<= 1) {
                const float    od = __shfl_xor(d, off, 64);
                const unsigned oj = __shfl_xor(j, off, 64);
                const bool take = (od > d) || (od == d && oj < j);
                d = take ? od : d;
                j = take ? oj : j;
            }
            if (col == 0) {
                const int i = irow0 + (r & 3) + 8 * (r >> 2) + 4 * half;
                partial[(size_t)(split * N_ + n) * HW_ + i] =
                    ((unsigned long long)j << 32) |
                    (unsigned long long)__float_as_uint(-2.f * d);
            }
        }
    }

    __threadfence();        // release partial
    grid.sync();
    __threadfence();        // acquire partial

    // ---------------- Phase 3: finalize ----------------------------------
    if (tid < 32) {
        const int id  = bid * 32 + tid;     // 0..16383
        const int n   = id >> 12;
        const int pix = id & 4095;
        float    fbd = 3.0e38f;
        unsigned fbj = 0u;
        #pragma unroll
        for (int sp = 0; sp < SPLITS_M; ++sp) {
            const unsigned long long v =
                partial[(size_t)(sp * N_ + n) * HW_ + pix];
            const float    d = __uint_as_float((unsigned)(v & 0xffffffffull));
            const unsigned j = (unsigned)(v >> 32);
            const bool take = (d < fbd) || (d == fbd && j < fbj);
            fbd = take ? d : fbd;
            fbj = take ? j : fbj;
        }
        out[n * 2 * HW_ + pix]            = (float)(fbj >> 6);          // idy
        out[n * 2 * HW_ + HW_ + pix]      = (float)(fbj & 63);          // idx
        out[N_ * 2 * HW_ + n * HW_ + pix] = fbd + qn[n * HW_ + pix];    // nnd
    }
}

// ===========================================================================
// Non-fused path (R16 kernels) — fallback if cooperative launch unavailable
// ===========================================================================
__global__ __launch_bounds__(256)
void build_desc_norms_kernel(const float* __restrict__ s,
                             const float* __restrict__ t,
                             f16* __restrict__ Qh, f16* __restrict__ Ql,
                             f16* __restrict__ Ph, f16* __restrict__ Pl,
                             float* __restrict__ pn,
                             float* __restrict__ qn) {
    const int y0  = blockIdx.x;
    const int n   = blockIdx.y;
    const int src = blockIdx.z;
    const float* img = (src ? s : t) + n * (C_ * HW_);
    f16* Dh = src ? Qh : Ph;
    f16* Dl = src ? Ql : Pl;
    float* nrm = src ? qn : pn;

    __shared__ float imgS[3][C_][W_];
    __shared__ float nS[4][W_];
    const int tid = threadIdx.x;
    #pragma unroll
    for (int k = 0; k < 3; ++k) {
        const int i4 = tid + k * 256;
        const int x4 = i4 & 15, c = (i4 >> 4) & 15, r = i4 >> 8;
        const int gy = iclamp(y0 + r - 1, 0, H_ - 1);
        const float4 v = *(const float4*)&img[c * HW_ + gy * W_ + x4 * 4];
        *(float4*)&imgS[r][c][x4 * 4] = v;
    }
    __syncthreads();

    const int q = tid >> 6, x = tid & 63;
    const int pix = y0 * W_ + x;
    float nacc = 0.f;
    #pragma unroll
    for (int u = 0; u < 5; ++u) {
        const int kk = q * 5 + u;
        if (kk < KK_) {
            f16x8 hv, lv;
            const int d  = kk >> 1;
            const int c0 = (kk & 1) * 8;
            const int dy = (d * 11) >> 5;
            const int dx = d - dy * 3;
            const int xs = iclamp(x + dx - 1, 0, W_ - 1);
            #pragma unroll
            for (int cc = 0; cc < 8; ++cc) {
                const float v = imgS[dy][c0 + cc][xs];
                const f16 h = (f16)v;
                hv[cc] = h;
                lv[cc] = (f16)(v - (float)h);
                nacc += v * v;
            }
            const size_t off = ((size_t)(n * KK_ + kk) * HW_ + pix) * 8;
            *(f16x8*)&Dh[off] = hv;
            *(f16x8*)&Dl[off] = lv;
        }
    }
    nS[q][x] = nacc;
    __syncthreads();
    if (tid < W_)
        nrm[n * HW_ + pix] = nS[0][tid] + nS[1][tid] + nS[2][tid] + nS[3][tid];
}

__global__ __launch_bounds__(256, 2)
void mfma_nn_kernel(const f16* __restrict__ Qh, const f16* __restrict__ Ql,
                    const f16* __restrict__ Ph, const f16* __restrict__ Pl,
                    const float* __restrict__ pn_g,
                    unsigned long long* __restrict__ partial) {
    const int bid   = blockIdx.x;
    const int split = bid & 3;
    const int n     = (bid >> 2) & 3;
    const int iblk  = bid >> 4;
    const int tid  = threadIdx.x;
    const int wave = tid >> 6, lane = tid & 63;
    const int col  = lane & 31;
    const int half = lane >> 5;
    const int irow0 = iblk * 128 + wave * 32;

    __shared__ f16 Bbuf[4][KK_ * KKSTRIDE];
    __shared__ float pnS[1024];

    f16x8 Ah[9], Al[9];
    #pragma unroll
    for (int c = 0; c < 9; ++c) {
        const size_t off = ((size_t)(n * KK_ + 2 * c + half) * HW_ +
                            irow0 + col) * 8;
        Ah[c] = *(const f16x8*)(Qh + off);
        Al[c] = *(const f16x8*)(Ql + off);
    }

    const int jsplit0 = split * 1024;
    #pragma unroll
    for (int k = 0; k < 4; ++k)
        pnS[tid + k * 256] = pn_g[n * HW_ + jsplit0 + tid + k * 256];

    float    bd[16];
    unsigned bj[16];
    #pragma unroll
    for (int r = 0; r < 16; ++r) { bd[r] = -3.0e38f; bj[r] = 0u; }

    const int stile = wave >> 1;
    const int skk0  = (wave & 1) * 9;
    const f16* sbase = half ? Pl : Ph;

    #define STAGE(PAIR, T0)                                                   \
        {   _Pragma("unroll")                                                 \
            for (int u = 0; u < 9; ++u) {                                     \
                const int kk = skk0 + u;                                      \
                const f16* g = sbase + ((size_t)(n * KK_ + kk) * HW_ +        \
                                        jsplit0 + ((T0) + stile) * 32 +       \
                                        col) * 8;                             \
                async_ld16(g, (void*)&Bbuf[(PAIR) * 2 + stile]                \
                                          [kk * KKSTRIDE + lane * 8]);        \
            }                                                                 \
        }

    #define BAR()                                                             \
        {   asm volatile("s_waitcnt vmcnt(0)" ::: "memory");                  \
            asm volatile("s_barrier" ::: "memory");                           \
        }

    #define COMPUTE2(PAIR, T0)                                                \
        {   const int j0 = (T0) * 32 + col;                                   \
            const float pnv0 = -0.5f * pnS[j0];                               \
            const float pnv1 = -0.5f * pnS[j0 + 32];                          \
            f32x16 C0, C1;                                                    \
            _Pragma("unroll")                                                 \
            for (int r = 0; r < 16; ++r) { C0[r] = pnv0; C1[r] = pnv1; }      \
            __builtin_amdgcn_s_setprio(1);                                    \
            _Pragma("unroll")                                                 \
            for (int c = 0; c < 9; ++c) {                                     \
                const int kb = (2 * c + half) * KKSTRIDE + col * 8;           \
                const f16x8 bh0 = *(const f16x8*)&Bbuf[(PAIR) * 2][kb];       \
                const f16x8 bl0 = *(const f16x8*)&Bbuf[(PAIR) * 2][kb + 256]; \
                const f16x8 bh1 = *(const f16x8*)&Bbuf[(PAIR) * 2 + 1][kb];   \
                const f16x8 bl1 = *(const f16x8*)&Bbuf[(PAIR) * 2 + 1]        \
                                                      [kb + 256];             \
                C0 = __builtin_amdgcn_mfma_f32_32x32x16_f16(                  \
                    Ah[c], bh0, C0, 0, 0, 0);                                 \
                C1 = __builtin_amdgcn_mfma_f32_32x32x16_f16(                  \
                    Ah[c], bh1, C1, 0, 0, 0);                                 \
                C0 = __builtin_amdgcn_mfma_f32_32x32x16_f16(                  \
                    Al[c], bh0, C0, 0, 0, 0);                                 \
                C1 = __builtin_amdgcn_mfma_f32_32x32x16_f16(                  \
                    Al[c], bh1, C1, 0, 0, 0);                                 \
                C0 = __builtin_amdgcn_mfma_f32_32x32x16_f16(                  \
                    Ah[c], bl0, C0, 0, 0, 0);                                 \
                C1 = __builtin_amdgcn_mfma_f32_32x32x16_f16(                  \
                    Ah[c], bl1, C1, 0, 0, 0);                                 \
            }                                                                 \
            __builtin_amdgcn_s_setprio(0);                                    \
            _Pragma("unroll")                                                 \
            for (int r = 0; r < 16; ++r) {                                    \
                if (C0[r] > bd[r]) { bd[r] = C0[r]; bj[r] = (unsigned)j0; }   \
                if (C1[r] > bd[r]) { bd[r] = C1[r];                           \
                                     bj[r] = (unsigned)(j0 + 32); }           \
            }                                                                 \
        }

    STAGE(0, 0)
    asm volatile("s_waitcnt vmcnt(0)" ::: "memory");
    __syncthreads();

    STAGE(1, 2)  COMPUTE2(0, 0)
    for (int gg = 0; gg < 6; ++gg) {
        const int t4 = gg * 4;
        BAR()  STAGE(0, t4 + 4)  COMPUTE2(1, t4 + 2)
        BAR()  STAGE(1, t4 + 6)  COMPUTE2(0, t4 + 4)
    }
    BAR()  STAGE(0, 28)  COMPUTE2(1, 26)
    BAR()  STAGE(1, 30)  COMPUTE2(0, 28)
    BAR()               COMPUTE2(1, 30)
    #undef STAGE
    #undef BAR
    #undef COMPUTE2

    #pragma unroll
    for (int r = 0; r < 16; ++r) {
        float    d = bd[r];
        unsigned j = (unsigned)jsplit0 + bj[r];
        #pragma unroll
        for (int off = 1; off < 32; off <<= 1) {
            const float    od = __shfl_xor(d, off, 64);
            const unsigned oj = __shfl_xor(j, off, 64);
            const bool take = (od > d) || (od == d && oj < j);
            d = take ? od : d;
            j = take ? oj : j;
        }
        if (col == 0) {
            const int i = irow0 + (r & 3) + 8 * (r >> 2) + 4 * half;
            partial[(size_t)(split * N_ + n) * HW_ + i] =
                ((unsigned long long)j << 32) |
                (unsigned long long)__float_as_uint(-2.f * d);
        }
    }
}

__global__ __launch_bounds__(256)
void finalize_mfma_kernel(const unsigned long long* __restrict__ partial,
                          const float* __restrict__ qn_g,
                          float* __restrict__ out) {
    const int id  = blockIdx.x * 256 + threadIdx.x;
    const int n   = id >> 12;
    const int pix = id & 4095;
    float    bd = 3.0e38f;
    unsigned bj = 0u;
    #pragma unroll
    for (int sp = 0; sp < SPLITS_M; ++sp) {
        const unsigned long long v = partial[(size_t)(sp * N_ + n) * HW_ + pix];
        const float    d = __uint_as_float((unsigned)(v & 0xffffffffull));
        const unsigned j = (unsigned)(v >> 32);
        const bool take = (d < bd) || (d == bd && j < bj);
        bd = take ? d : bd;
        bj = take ? j : bj;
    }
    out[n * 2 * HW_ + pix]            = (float)(bj >> 6);
    out[n * 2 * HW_ + HW_ + pix]      = (float)(bj & 63);
    out[N_ * 2 * HW_ + n * HW_ + pix] = bd + qn_g[n * HW_ + pix];
}

// ===========================================================================
// fp32 vector fallback — unchanged
// ===========================================================================
__global__ __launch_bounds__(256)
void prep_norms_kernel(const float* __restrict__ s,
                       const float* __restrict__ t,
                       float* __restrict__ pn,
                       float* __restrict__ qn) {
    const int gid   = blockIdx.x * 256 + threadIdx.x;
    const int which = gid >> 14;
    const int id    = gid & 16383;
    const int n     = id >> 12;
    const int pix   = id & 4095;
    const int y = pix >> 6, x = pix & 63;
    const float* base = (which ? s : t) + n * (C_ * HW_);
    float acc = 0.f;
    for (int c = 0; c < C_; ++c) {
        const float* bc = base + c * HW_;
        #pragma unroll
        for (int dy = 0; dy < 3; ++dy) {
            const float* br = bc + iclamp(y + dy - 1, 0, H_ - 1) * W_;
            #pragma unroll
            for (int dx = 0; dx < 3; ++dx) {
                float v = br[iclamp(x + dx - 1, 0, W_ - 1)];
                acc += v * v;
            }
        }
    }
    (which ? qn : pn)[id] = acc;
}

__global__ __launch_bounds__(256)
void patchmatch_main_kernel(const float* __restrict__ s,
                            const float* __restrict__ t,
                            const float* __restrict__ pn_g,
                            const float* __restrict__ qn_g,
                            unsigned long long* __restrict__ partial) {
    const int yq    = blockIdx.x;
    const int n     = blockIdx.y;
    const int split = blockIdx.z;
    const int tid  = threadIdx.x;
    const int tx   = tid & 15;
    const int ty   = tid >> 4;
    const int i0   = ty * 4;
    const int jrow = tx >> 2;
    const int jx0  = (tx & 3) * 16;

    __shared__ float qS[C_][3][68];
    __shared__ float tS[C_][6][68];
    __shared__ float qnS[W_];

    const float* sb = s + n * (C_ * HW_);
    const float* tb = t + n * (C_ * HW_);

    #pragma unroll
    for (int k = 0; k < 3; ++k) {
        const int id = tid + k * 256;
        const int sg = id & 15;
        const int c  = (id >> 4) & 15;
        const int r  = id >> 8;
        const int gr = iclamp(yq + r - 1, 0, H_ - 1);
        const float4 v = *(const float4*)&sb[c * HW_ + gr * W_ + sg * 4];
        float* dst = &qS[c][r][1 + sg * 4];
        dst[0] = v.x; dst[1] = v.y; dst[2] = v.z; dst[3] = v.w;
    }
    if (tid < 48) {
        const int c  = tid & 15;
        const int r  = tid >> 4;
        const int gr = iclamp(yq + r - 1, 0, H_ - 1);
        qS[c][r][0]  = sb[c * HW_ + gr * W_];
        qS[c][r][65] = sb[c * HW_ + gr * W_ + 63];
    }
    if (tid < W_) qnS[tid] = qn_g[n * HW_ + yq * W_ + tid];

    unsigned long long best[4] = {~0ull, ~0ull, ~0ull, ~0ull};

    for (int ytl = 0; ytl < TILES_PER_SPLIT_V; ++ytl) {
        const int yt = split * TILES_PER_SPLIT_V + ytl;
        __syncthreads();
        #pragma unroll
        for (int k = 0; k < 6; ++k) {
            const int id = tid + k * 256;
            const int sg = id & 15;
            const int c  = (id >> 4) & 15;
            const int r  = id >> 8;
            const int gr = iclamp(4 * yt + r - 1, 0, H_ - 1);
            const float4 v = *(const float4*)&tb[c * HW_ + gr * W_ + sg * 4];
            float* dst = &tS[c][r][1 + sg * 4];
            dst[0] = v.x; dst[1] = v.y; dst[2] = v.z; dst[3] = v.w;
        }
        if (tid < 96) {
            const int c  = tid & 15;
            const int r  = tid >> 4;
            const int gr = iclamp(4 * yt + r - 1, 0, H_ - 1);
            tS[c][r][0]  = tb[c * HW_ + gr * W_];
            tS[c][r][65] = tb[c * HW_ + gr * W_ + 63];
        }
        __syncthreads();

        float acc[4][16];
        #pragma unroll
        for (int a = 0; a < 4; ++a)
            #pragma unroll
            for (int b = 0; b < 16; ++b) acc[a][b] = 0.f;

        for (int c = 0; c < C_; ++c) {
            #pragma unroll
            for (int dy = 0; dy < 3; ++dy) {
                float qv[6], tv[18];
                *(float4*)&qv[0] = *(const float4*)&qS[c][dy][i0];
                *(float2*)&qv[4] = *(const float2*)&qS[c][dy][i0 + 4];
                const float* trow = &tS[c][jrow + dy][jx0];
                *(float4*)&tv[0]  = *(const float4*)&trow[0];
                *(float4*)&tv[4]  = *(const float4*)&trow[4];
                *(float4*)&tv[8]  = *(const float4*)&trow[8];
                *(float4*)&tv[12] = *(const float4*)&trow[12];
                *(float2*)&tv[16] = *(const float2*)&trow[16];
                #pragma unroll
                for (int dx = 0; dx < 3; ++dx)
                    #pragma unroll
                    for (int a = 0; a < 4; ++a)
                        #pragma unroll
                        for (int b = 0; b < 16; ++b)
                            acc[a][b] += qv[a + dx] * tv[b + dx];
            }
        }

        const int jbase = yt * 256 + jrow * W_ + jx0;
        float pnv[16];
        const float* png = &pn_g[n * HW_ + jbase];
        *(float4*)&pnv[0]  = *(const float4*)&png[0];
        *(float4*)&pnv[4]  = *(const float4*)&png[4];
        *(float4*)&pnv[8]  = *(const float4*)&png[8];
        *(float4*)&pnv[12] = *(const float4*)&png[12];
        #pragma unroll
        for (int a = 0; a < 4; ++a) {
            const float qn = qnS[i0 + a];
            #pragma unroll
            for (int b = 0; b < 16; ++b) {
                const float d2 = qn + pnv[b] - 2.f * acc[a][b];
                unsigned long long cand =
                    ((unsigned long long)__float_as_uint(d2) << 32) |
                    (unsigned)(jbase + b);
                best[a] = cand < best[a] ? cand : best[a];
            }
        }
    }

    #pragma unroll
    for (int a = 0; a < 4; ++a) {
        unsigned long long v = best[a];
        #pragma unroll
        for (int mm = 8; mm >= 1; mm >>= 1) {
            unsigned long long o = __shfl_xor(v, mm, 64);
            v = o < v ? o : v;
        }
        best[a] = v;
    }
    if (tx == 0) {
        #pragma unroll
        for (int a = 0; a < 4; ++a)
            partial[((split * N_ + n) * HW_) + yq * W_ + i0 + a] = best[a];
    }
}

__global__ __launch_bounds__(256)
void finalize_kernel(const unsigned long long* __restrict__ partial,
                     float* __restrict__ out) {
    const int id  = blockIdx.x * 256 + threadIdx.x;
    const int n   = id >> 12;
    const int pix = id & 4095;
    unsigned long long best = ~0ull;
    #pragma unroll
    for (int sp = 0; sp < SPLITS_V; ++sp) {
        unsigned long long v = partial[(sp * N_ + n) * HW_ + pix];
        best = v < best ? v : best;
    }
    const unsigned j = (unsigned)(best & 0xffffffffu);
    const float d2 = __uint_as_float((unsigned)(best >> 32));
    out[n * 2 * HW_ + pix]            = (float)(j >> 6);
    out[n * 2 * HW_ + HW_ + pix]      = (float)(j & 63);
    out[N_ * 2 * HW_ + n * HW_ + pix] = d2;
}

__global__ __launch_bounds__(256)
void patchmatch_mono_kernel(const float* __restrict__ s,
                            const float* __restrict__ t,
                            float* __restrict__ out) {
    const int yq  = blockIdx.x;
    const int n   = blockIdx.y;
    const int tid = threadIdx.x;
    const int tx  = tid & 15;
    const int ty  = tid >> 4;
    const int i0  = ty * 4;
    const int jrow = tx >> 3;
    const int jx0  = (tx & 7) * 8;

    __shared__ float qS[C_][3][68];
    __shared__ float tS[C_][4][68];
    __shared__ float pnS[HW_];
    __shared__ float qnS[W_];

    const float* sb = s + n * (C_ * HW_);
    const float* tb = t + n * (C_ * HW_);

    for (int jj = tid; jj < HW_; jj += 256) {
        const int y = jj >> 6, x = jj & 63;
        float acc = 0.f;
        for (int c = 0; c < C_; ++c) {
            const float* tc = tb + c * HW_;
            #pragma unroll
            for (int dy = 0; dy < 3; ++dy) {
                const float* tr = tc + iclamp(y + dy - 1, 0, H_ - 1) * W_;
                #pragma unroll
                for (int dx = 0; dx < 3; ++dx) {
                    float v = tr[iclamp(x + dx - 1, 0, W_ - 1)];
                    acc += v * v;
                }
            }
        }
        pnS[jj] = acc;
    }
    for (int idx = tid; idx < C_ * 3 * 66; idx += 256) {
        const int c   = idx / (3 * 66);
        const int rem = idx - c * (3 * 66);
        const int rr  = rem / 66;
        const int xi  = rem - rr * 66;
        qS[c][rr][xi] = sb[c * HW_ + iclamp(yq + rr - 1, 0, H_ - 1) * W_ +
                           iclamp(xi - 1, 0, W_ - 1)];
    }
    __syncthreads();
    if (tid < W_) {
        float acc = 0.f;
        for (int c = 0; c < C_; ++c)
            #pragma unroll
            for (int dy = 0; dy < 3; ++dy)
                #pragma unroll
                for (int dx = 0; dx < 3; ++dx) {
                    float v = qS[c][dy][tid + dx];
                    acc += v * v;
                }
        qnS[tid] = acc;
    }

    unsigned long long best[4] = {~0ull, ~0ull, ~0ull, ~0ull};
    for (int yt = 0; yt < 32; ++yt) {
        __syncthreads();
        for (int idx = tid; idx < C_ * 4 * 66; idx += 256) {
            const int c   = idx / (4 * 66);
            const int rem = idx - c * (4 * 66);
            const int rr  = rem / 66;
            const int xi  = rem - rr * 66;
            tS[c][rr][xi] = tb[c * HW_ + iclamp(2 * yt + rr - 1, 0, H_ - 1) * W_ +
                               iclamp(xi - 1, 0, W_ - 1)];
        }
        __syncthreads();

        float acc[4][8];
        #pragma unroll
        for (int a = 0; a < 4; ++a)
            #pragma unroll
            for (int b = 0; b < 8; ++b) acc[a][b] = 0.f;

        for (int c = 0; c < C_; ++c) {
            #pragma unroll
            for (int dy = 0; dy < 3; ++dy) {
                float qv[8], tv[12];
                *(float4*)&qv[0] = *(const float4*)&qS[c][dy][i0];
                *(float4*)&qv[4] = *(const float4*)&qS[c][dy][i0 + 4];
                const float* trow = &tS[c][jrow + dy][jx0];
                *(float4*)&tv[0] = *(const float4*)&trow[0];
                *(float4*)&tv[4] = *(const float4*)&trow[4];
                *(float4*)&tv[8] = *(const float4*)&trow[8];
                #pragma unroll
                for (int dx = 0; dx < 3; ++dx)
                    #pragma unroll
                    for (int a = 0; a < 4; ++a)
                        #pragma unroll
                        for (int b = 0; b < 8; ++b)
                            acc[a][b] += qv[a + dx] * tv[b + dx];
            }
        }
        const int rbase = (2 * yt + jrow) * W_ + jx0;
        #pragma unroll
        for (int a = 0; a < 4; ++a) {
            const float qn = qnS[i0 + a];
            #pragma unroll
            for (int b = 0; b < 8; ++b) {
                const int j = rbase + b;
                const float d2 = qn + pnS[j] - 2.f * acc[a][b];
                unsigned long long cand =
                    ((unsigned long long)__float_as_uint(d2) << 32) | (unsigned)j;
                best[a] = cand < best[a] ? cand : best[a];
            }
        }
    }
    #pragma unroll
    for (int a = 0; a < 4; ++a) {
        unsigned long long v = best[a];
        #pragma unroll
        for (int mm = 8; mm >= 1; mm >>= 1) {
            unsigned long long o = __shfl_xor(v, mm, 64);
            v = o < v ? o : v;
        }
        best[a] = v;
    }
    if (tx == 0) {
        #pragma unroll
        for (int a = 0; a < 4; ++a) {
            const int x = i0 + a;
            const unsigned j = (unsigned)(best[a] & 0xffffffffu);
            const float d2 = __uint_as_float((unsigned)(best[a] >> 32));
            const int pix = yq * W_ + x;
            out[n * 2 * HW_ + pix]            = (float)(j >> 6);
            out[n * 2 * HW_ + HW_ + pix]      = (float)(j & 63);
            out[N_ * 2 * HW_ + n * HW_ + pix] = d2;
        }
    }
}

// ===========================================================================
extern "C" void kernel_launch(void* const* d_in, const int* in_sizes, int n_in,
                              void* d_out, int out_size, void* d_ws, size_t ws_size,
                              hipStream_t stream) {
    const float* s = (const float*)d_in[0];
    const float* t = (const float*)d_in[1];
    float* out = (float*)d_out;

    // MFMA ws layout:
    //   pn [4][4096] f32 | qn [4][4096] f32 | partial [4][4][4096] u64 |
    //   Qh | Ql | Ph | Pl   each K-major [4][18][4096][8] f16 (4.72 MB)
    const size_t norm_b  = (size_t)N_ * HW_ * 4;
    const size_t part_b  = (size_t)SPLITS_M * N_ * HW_ * 8;
    const size_t desc_b  = (size_t)N_ * HW_ * KK_ * 8 * 2;
    const size_t need_m  = 2 * norm_b + part_b + 4 * desc_b;     // ~19.5 MB

    if (ws_size >= need_m) {
        char* w = (char*)d_ws;
        float* pn = (float*)w;                       w += norm_b;
        float* qn = (float*)w;                       w += norm_b;
        unsigned long long* partial = (unsigned long long*)w; w += part_b;
        f16* Qh = (f16*)w;  w += desc_b;
        f16* Ql = (f16*)w;  w += desc_b;
        f16* Ph = (f16*)w;  w += desc_b;
        f16* Pl = (f16*)w;

        // --- try fused cooperative path (512 blocks = 2/CU co-resident) ---
        static int coop_state = -1;     // -1 unknown, 0 no, 1 yes
        if (coop_state == -1) {
            int nb = 0;
            hipError_t qe = hipOccupancyMaxActiveBlocksPerMultiprocessor(
                &nb, fused_nn_kernel, 256, 0);
            coop_state = (qe == hipSuccess && nb >= 2) ? 1 : 0;
        }
        if (coop_state == 1) {
            void* args[] = {(void*)&s, (void*)&t, (void*)&Qh, (void*)&Ql,
                            (void*)&Ph, (void*)&Pl, (void*)&pn, (void*)&qn,
                            (void*)&partial, (void*)&out};
            hipError_t le = hipLaunchCooperativeKernel(
                (const void*)fused_nn_kernel, dim3(512), dim3(256),
                args, 0, stream);
            if (le == hipSuccess) return;
            coop_state = 0;             // remember failure, fall through
        }

        // --- fallback: 3-kernel path (R16) ---
        build_desc_norms_kernel<<<dim3(64, N_, 2), 256, 0, stream>>>(
            s, t, Qh, Ql, Ph, Pl, pn, qn);
        mfma_nn_kernel<<<512, 256, 0, stream>>>(Qh, Ql, Ph, Pl, pn, partial);
        finalize_mfma_kernel<<<64, 256, 0, stream>>>(partial, qn, out);
        return;
    }

    // Fallback: fp32 vector path
    const size_t need_v = 2 * norm_b + (size_t)SPLITS_V * N_ * HW_ * 8;
    if (ws_size >= need_v) {
        float* pn = (float*)d_ws;
        float* qn = pn + N_ * HW_;
        unsigned long long* partial =
            (unsigned long long*)((char*)d_ws + 2 * norm_b);
        prep_norms_kernel<<<128, 256, 0, stream>>>(s, t, pn, qn);
        dim3 grid(H_, N_, SPLITS_V);
        patchmatch_main_kernel<<<grid, 256, 0, stream>>>(s, t, pn, qn, partial);
        finalize_kernel<<<64, 256, 0, stream>>>(partial, out);
        return;
    }

    dim3 grid(H_, N_);
    patchmatch_mono_kernel<<<grid, 256, 0, stream>>>(s, t, out);
}